// Round 1
// baseline (732.960 us; speedup 1.0000x reference)
//
#include <hip/hip_runtime.h>
#include <hip/hip_bf16.h>
#include <math.h>

// Problem constants
#define B_    32
#define DIM_  64
#define NP_   4
#define D_    1024
#define E_    768
#define VC_   32000
#define R_    2048          // B_*DIM_
#define KTOP  2
#define EPS_  1e-8f
#define NCB   250           // 32000 / 128 v-blocks in scores GEMM
#define NCAND 8

// Workspace layout (float offsets), ~221 MB total
#define T_OFF    ((size_t)0)
#define S_OFF    (T_OFF + (size_t)VC_ * D_)          // 32,768,000
#define INVW_OFF (S_OFF + (size_t)R_ * D_)           // 34,865,152
#define INVP_OFF (INVW_OFF + VC_)
#define WSQ_OFF  (INVP_OFF + R_)
#define PV_OFF   (WSQ_OFF + VC_)
#define PI_OFF   (PV_OFF + (size_t)R_ * NCB * 2)
#define SB_OFF   (PI_OFF + (size_t)R_ * NCB * 2)     // ushort region, R_*D_ ushorts
#define TB_OFF   (SB_OFF + (size_t)R_ * D_ / 2)      // ushort region, VC_*D_ ushorts
#define WH_OFF   (TB_OFF + (size_t)VC_ * D_ / 2)     // ushort region, D_*E_ ushorts
#define WL_OFF   (WH_OFF + (size_t)D_ * E_ / 2)
#define CAND_OFF (WL_OFF + (size_t)D_ * E_ / 2)
#define TIDX_OFF (CAND_OFF + (size_t)R_ * NCAND)

#define NEG_INF (-3.4e38f)

typedef __bf16 bf16x8 __attribute__((ext_vector_type(8)));
typedef unsigned short u16x8 __attribute__((ext_vector_type(8)));
typedef float  f32x4  __attribute__((ext_vector_type(4)));

__device__ __forceinline__ unsigned short f2bf(float f) {
    unsigned u = __float_as_uint(f);
    u += 0x7fffu + ((u >> 16) & 1u);           // round-to-nearest-even
    return (unsigned short)(u >> 16);
}

// global -> LDS direct copy, 16B per lane. LDS dest = wave-uniform base + lane*16.
__device__ __forceinline__ void async_ld16(const void* gptr, void* lptr) {
    __builtin_amdgcn_global_load_lds(
        (const __attribute__((address_space(1))) void*)(uintptr_t)gptr,
        (__attribute__((address_space(3))) void*)(unsigned)(uintptr_t)lptr,
        16, 0, 0);
}

__device__ __forceinline__ bool better(float v, int i, float bv, int bi) {
    return (v > bv) || (v == bv && i < bi);
}

// ---------------------------------------------------------------------------
// Kernel Z0: zero the wsq accumulator (ws is poisoned before every launch)
// ---------------------------------------------------------------------------
__global__ __launch_bounds__(256) void k_zero(float* __restrict__ wsq) {
    int i = blockIdx.x * 256 + threadIdx.x;
    if (i < VC_) wsq[i] = 0.f;
}

// ---------------------------------------------------------------------------
// Kernel S0: split we (fp32 [D,E]) into bf16 hi/lo
// ---------------------------------------------------------------------------
__global__ __launch_bounds__(256) void k_split_we(const float* __restrict__ x,
                                                  unsigned short* __restrict__ hi,
                                                  unsigned short* __restrict__ lo) {
    int i = (blockIdx.x * 256 + threadIdx.x) * 4;   // grid sized exactly: D_*E_/1024 blocks
    float4 v = *(const float4*)(x + i);
    ushort4 h, l;
    float e;
    h.x = f2bf(v.x); e = v.x - __uint_as_float((unsigned)h.x << 16); l.x = f2bf(e);
    h.y = f2bf(v.y); e = v.y - __uint_as_float((unsigned)h.y << 16); l.y = f2bf(e);
    h.z = f2bf(v.z); e = v.z - __uint_as_float((unsigned)h.z << 16); l.z = f2bf(e);
    h.w = f2bf(v.w); e = v.w - __uint_as_float((unsigned)h.w << 16); l.w = f2bf(e);
    *(ushort4*)(hi + i) = h;
    *(ushort4*)(lo + i) = l;
}

// ---------------------------------------------------------------------------
// Kernel A: s[r,d] = sum_np P[r,np,d]; sb = bf16(s); invp[r] = 1/max(||P_r||,eps)
// ---------------------------------------------------------------------------
__global__ __launch_bounds__(256) void k_sum_pnorm(const float* __restrict__ P,
                                                   float* __restrict__ s,
                                                   unsigned short* __restrict__ sb,
                                                   float* __restrict__ invp) {
    int r = blockIdx.x;
    int t = threadIdx.x;
    const float* base = P + (size_t)r * NP_ * D_;
    float4 acc = make_float4(0.f, 0.f, 0.f, 0.f);
    float sq = 0.f;
#pragma unroll
    for (int np = 0; np < NP_; ++np) {
        float4 v = *(const float4*)(base + (size_t)np * D_ + t * 4);
        acc.x += v.x; acc.y += v.y; acc.z += v.z; acc.w += v.w;
        sq += v.x * v.x + v.y * v.y + v.z * v.z + v.w * v.w;
    }
    *(float4*)(s + (size_t)r * D_ + t * 4) = acc;
    ushort4 o;
    o.x = f2bf(acc.x); o.y = f2bf(acc.y); o.z = f2bf(acc.z); o.w = f2bf(acc.w);
    *(ushort4*)(sb + (size_t)r * D_ + t * 4) = o;

    __shared__ float red[256];
    red[t] = sq;
    __syncthreads();
    for (int off = 128; off > 0; off >>= 1) {
        if (t < off) red[t] += red[t + off];
        __syncthreads();
    }
    if (t == 0) invp[r] = 1.0f / fmaxf(sqrtf(red[0]), EPS_);
}

// ---------------------------------------------------------------------------
// Kernel B: split-bf16 MFMA GEMM.
//   T[v,d] = dot(few[v,:], we[d,:]) + bias[v]  via  Ah*Bh + Al*Bh + Ah*Bl
// A (few) staged fp32 via global_load_lds, split to hi/lo fragments in-register.
// B (we) pre-split bf16 hi/lo. Epilogue writes T (fp32), Tb (bf16) and
// accumulates per-row sumsq into wsq via atomics.
// Tile 128(v) x 128(d), BK=32, 4 waves.
// ---------------------------------------------------------------------------
__global__ __launch_bounds__(256) void k_gemm_T_mfma(const float* __restrict__ A,      // few [VC,E]
                                                     const unsigned short* __restrict__ Bh, // weh [D,E]
                                                     const unsigned short* __restrict__ Bl, // wel [D,E]
                                                     const float* __restrict__ bias,
                                                     float* __restrict__ T,
                                                     unsigned short* __restrict__ Tb,
                                                     float* __restrict__ wsq) {
    __shared__ __align__(16) float          Af[128 * 32];   // 16 KB, [v-row][k] fp32
    __shared__ __align__(16) unsigned short Bsh[128 * 32];  //  8 KB
    __shared__ __align__(16) unsigned short Bsl[128 * 32];  //  8 KB

    int tid = threadIdx.x;
    int wid = tid >> 6, lane = tid & 63;
    int quad = lane >> 4, l15 = lane & 15;
    int v0 = blockIdx.y * 128;
    int d0 = blockIdx.x * 128;
    int vband = (wid & 1) * 64, nband = (wid >> 1) * 64;

    f32x4 acc[4][4];
#pragma unroll
    for (int i = 0; i < 4; ++i)
#pragma unroll
        for (int j = 0; j < 4; ++j) acc[i][j] = f32x4{0.f, 0.f, 0.f, 0.f};

    int arow = wid * 32 + (lane >> 3);   // fp32 staging: 8 rows per wave-issue
    int acol = (lane & 7) * 4;           // float offset (16 B)
    int brow = wid * 32 + (lane >> 2);   // bf16 staging: 16 rows per wave-issue
    int bcol = (lane & 3) * 8;           // ushort offset (16 B)

    for (int k0 = 0; k0 < E_; k0 += 32) {
#pragma unroll
        for (int j = 0; j < 4; ++j)
            async_ld16(A + (size_t)(v0 + arow + j * 8) * E_ + k0 + acol,
                       (void*)(Af + (wid * 32 + j * 8) * 32));
#pragma unroll
        for (int j = 0; j < 2; ++j) {
            async_ld16(Bh + (size_t)(d0 + brow + j * 16) * E_ + k0 + bcol,
                       (void*)(Bsh + (wid * 32 + j * 16) * 32));
            async_ld16(Bl + (size_t)(d0 + brow + j * 16) * E_ + k0 + bcol,
                       (void*)(Bsl + (wid * 32 + j * 16) * 32));
        }
        __syncthreads();

        bf16x8 bh[4], bl[4];
#pragma unroll
        for (int nt = 0; nt < 4; ++nt) {
            bh[nt] = *(const bf16x8*)(Bsh + (nband + nt * 16 + l15) * 32 + quad * 8);
            bl[nt] = *(const bf16x8*)(Bsl + (nband + nt * 16 + l15) * 32 + quad * 8);
        }
#pragma unroll
        for (int mt = 0; mt < 4; ++mt) {
            const float* ap = Af + (vband + mt * 16 + l15) * 32 + quad * 8;
            f32x4 xa = *(const f32x4*)ap;
            f32x4 xb = *(const f32x4*)(ap + 4);
            u16x8 hu, lu;
#pragma unroll
            for (int e = 0; e < 4; ++e) {
                unsigned short h0 = f2bf(xa[e]);
                unsigned short h1 = f2bf(xb[e]);
                hu[e] = h0; hu[e + 4] = h1;
                lu[e]     = f2bf(xa[e] - __uint_as_float((unsigned)h0 << 16));
                lu[e + 4] = f2bf(xb[e] - __uint_as_float((unsigned)h1 << 16));
            }
            bf16x8 ah = __builtin_bit_cast(bf16x8, hu);
            bf16x8 al = __builtin_bit_cast(bf16x8, lu);
#pragma unroll
            for (int nt = 0; nt < 4; ++nt) {
                acc[mt][nt] = __builtin_amdgcn_mfma_f32_16x16x32_bf16(ah, bh[nt], acc[mt][nt], 0, 0, 0);
                acc[mt][nt] = __builtin_amdgcn_mfma_f32_16x16x32_bf16(al, bh[nt], acc[mt][nt], 0, 0, 0);
                acc[mt][nt] = __builtin_amdgcn_mfma_f32_16x16x32_bf16(ah, bl[nt], acc[mt][nt], 0, 0, 0);
            }
        }
        __syncthreads();
    }

    // Epilogue: T fp32, Tb bf16, row-sumsq partials -> wsq atomics
    float sq[4][4] = {};
#pragma unroll
    for (int mt = 0; mt < 4; ++mt) {
        int vbase = v0 + vband + mt * 16 + quad * 4;
        float bv[4];
#pragma unroll
        for (int rg = 0; rg < 4; ++rg) bv[rg] = bias[vbase + rg];
#pragma unroll
        for (int nt = 0; nt < 4; ++nt) {
            int d = d0 + nband + nt * 16 + l15;
#pragma unroll
            for (int rg = 0; rg < 4; ++rg) {
                float val = acc[mt][nt][rg] + bv[rg];
                T[(size_t)(vbase + rg) * D_ + d] = val;
                Tb[(size_t)(vbase + rg) * D_ + d] = f2bf(val);
                sq[mt][rg] += val * val;
            }
        }
    }
#pragma unroll
    for (int mt = 0; mt < 4; ++mt)
#pragma unroll
        for (int rg = 0; rg < 4; ++rg) {
            float p = sq[mt][rg];
            p += __shfl_xor(p, 1); p += __shfl_xor(p, 2);
            p += __shfl_xor(p, 4); p += __shfl_xor(p, 8);
            if (l15 == 0) atomicAdd(&wsq[v0 + vband + mt * 16 + quad * 4 + rg], p);
        }
}

// ---------------------------------------------------------------------------
// Kernel W: invw[v] = 1 / max(2*sqrt(wsq[v]), eps)
// ---------------------------------------------------------------------------
__global__ __launch_bounds__(256) void k_invw(const float* __restrict__ wsq,
                                              float* __restrict__ invw) {
    int v = blockIdx.x * 256 + threadIdx.x;
    if (v < VC_) invw[v] = 1.0f / fmaxf(2.0f * sqrtf(wsq[v]), EPS_);
}

// ---------------------------------------------------------------------------
// Kernel C: bf16 MFMA candidate GEMM. Tile 128(v) x 128(r), BK=32.
// Tb is UNSCALED bf16(T); invw applied in the epilogue before ranking.
// Emits per-(r, v-block) top-2 partials (approx values, used only to nominate).
// ---------------------------------------------------------------------------
__global__ __launch_bounds__(256) void k_scores_mfma(const unsigned short* __restrict__ Tb,
                                                     const unsigned short* __restrict__ sb,
                                                     const float* __restrict__ invw,
                                                     float* __restrict__ pval,
                                                     int* __restrict__ pidx) {
    __shared__ __align__(16) unsigned short As[128 * 32];  // [v-row][k]
    __shared__ __align__(16) unsigned short Bs[128 * 32];  // [r-row][k]
    __shared__ float mv[2][128][2];
    __shared__ int   mi[2][128][2];

    int tid = threadIdx.x;
    int wid = tid >> 6, lane = tid & 63;
    int quad = lane >> 4, l15 = lane & 15;
    int v0 = blockIdx.x * 128;
    int r0 = blockIdx.y * 128;
    int vband = (wid & 1) * 64, rband = (wid >> 1) * 64;

    f32x4 acc[4][4];
#pragma unroll
    for (int i = 0; i < 4; ++i)
#pragma unroll
        for (int j = 0; j < 4; ++j) acc[i][j] = f32x4{0.f, 0.f, 0.f, 0.f};

    int srow  = wid * 32 + (lane >> 2);
    int skoff = (lane & 3) * 8;

    for (int k0 = 0; k0 < D_; k0 += 32) {
#pragma unroll
        for (int j = 0; j < 2; ++j) {
            async_ld16(Tb + (size_t)(v0 + srow + j * 16) * D_ + k0 + skoff,
                       (void*)(As + (wid * 32 + j * 16) * 32));
            async_ld16(sb + (size_t)(r0 + srow + j * 16) * D_ + k0 + skoff,
                       (void*)(Bs + (wid * 32 + j * 16) * 32));
        }
        __syncthreads();
        bf16x8 af[4], bf[4];
#pragma unroll
        for (int mt = 0; mt < 4; ++mt)
            af[mt] = *(const bf16x8*)(As + (vband + mt * 16 + l15) * 32 + quad * 8);
#pragma unroll
        for (int nt = 0; nt < 4; ++nt)
            bf[nt] = *(const bf16x8*)(Bs + (rband + nt * 16 + l15) * 32 + quad * 8);
#pragma unroll
        for (int mt = 0; mt < 4; ++mt)
#pragma unroll
            for (int nt = 0; nt < 4; ++nt)
                acc[mt][nt] = __builtin_amdgcn_mfma_f32_16x16x32_bf16(af[mt], bf[nt], acc[mt][nt], 0, 0, 0);
        __syncthreads();
    }

    // Epilogue: scale by invw[v], per r top-2 over this block's 128 v's.
    float iw[4][4];
#pragma unroll
    for (int mt = 0; mt < 4; ++mt)
#pragma unroll
        for (int rg = 0; rg < 4; ++rg)
            iw[mt][rg] = invw[v0 + vband + mt * 16 + quad * 4 + rg];

#pragma unroll
    for (int nt = 0; nt < 4; ++nt) {
        float b1 = NEG_INF, b2 = NEG_INF;
        int i1 = 0x7fffffff, i2 = 0x7fffffff;
#pragma unroll
        for (int mt = 0; mt < 4; ++mt)
#pragma unroll
            for (int rg = 0; rg < 4; ++rg) {
                float val = acc[mt][nt][rg] * iw[mt][rg];
                int v = v0 + vband + mt * 16 + quad * 4 + rg;
                if (better(val, v, b1, i1)) { b2 = b1; i2 = i1; b1 = val; i1 = v; }
                else if (better(val, v, b2, i2)) { b2 = val; i2 = v; }
            }
#pragma unroll
        for (int off = 16; off <= 32; off <<= 1) {
            float o1 = __shfl_xor(b1, off), o2 = __shfl_xor(b2, off);
            int  oi1 = __shfl_xor(i1, off), oi2 = __shfl_xor(i2, off);
            if (better(o1, oi1, b1, i1)) {
                if (better(b1, i1, o2, oi2)) { b2 = b1; i2 = i1; } else { b2 = o2; i2 = oi2; }
                b1 = o1; i1 = oi1;
            } else if (better(o1, oi1, b2, i2)) { b2 = o1; i2 = oi1; }
        }
        if (quad == 0) {
            int rl = rband + nt * 16 + l15;
            mv[wid & 1][rl][0] = b1; mi[wid & 1][rl][0] = i1;
            mv[wid & 1][rl][1] = b2; mi[wid & 1][rl][1] = i2;
        }
    }
    __syncthreads();
    if (tid < 128) {
        float b1 = mv[0][tid][0], b2 = mv[0][tid][1];
        int   i1 = mi[0][tid][0], i2 = mi[0][tid][1];
#pragma unroll
        for (int sl = 0; sl < 2; ++sl) {
            float o = mv[1][tid][sl]; int oi = mi[1][tid][sl];
            if (better(o, oi, b1, i1)) { b2 = b1; i2 = i1; b1 = o; i1 = oi; }
            else if (better(o, oi, b2, i2)) { b2 = o; i2 = oi; }
        }
        size_t off = ((size_t)(r0 + tid) * NCB + blockIdx.x) * 2;
        pval[off] = b1;     pidx[off] = i1;
        pval[off + 1] = b2; pidx[off + 1] = i2;
    }
}

// ---------------------------------------------------------------------------
// Kernel D: top-8 candidates per row from the 500 partials (approx ranking)
// ---------------------------------------------------------------------------
__global__ __launch_bounds__(256) void k_topk8(const float* __restrict__ pval,
                                               const int* __restrict__ pidx,
                                               int* __restrict__ cands) {
    int r = blockIdx.x, t = threadIdx.x;
    __shared__ float v[512];
    __shared__ int  id[512];
    for (int c = t; c < 512; c += 256) {
        if (c < NCB * 2) { v[c] = pval[(size_t)r * NCB * 2 + c]; id[c] = pidx[(size_t)r * NCB * 2 + c]; }
        else             { v[c] = NEG_INF; id[c] = 0x7fffffff; }
    }
    __syncthreads();
    if (t == 0) {
        float bv[NCAND]; int bi[NCAND];
#pragma unroll
        for (int j = 0; j < NCAND; ++j) { bv[j] = NEG_INF; bi[j] = 0x7fffffff; }
        for (int c = 0; c < NCB * 2; ++c) {
            float x = v[c]; int xi = id[c];
            if (better(x, xi, bv[NCAND - 1], bi[NCAND - 1])) {
                int j = NCAND - 1;
                while (j > 0 && better(x, xi, bv[j - 1], bi[j - 1])) {
                    bv[j] = bv[j - 1]; bi[j] = bi[j - 1]; --j;
                }
                bv[j] = x; bi[j] = xi;
            }
        }
#pragma unroll
        for (int j = 0; j < NCAND; ++j) cands[r * NCAND + j] = bi[j];
    }
}

// ---------------------------------------------------------------------------
// Kernel E: exact fp32 rescore of 8 candidates/row -> final top-2 + values
// ---------------------------------------------------------------------------
__global__ __launch_bounds__(256) void k_rescore(const float* __restrict__ s,
                                                 const float* __restrict__ T,
                                                 const int* __restrict__ cands,
                                                 const float* __restrict__ invw,
                                                 const float* __restrict__ invp,
                                                 float* __restrict__ outv,
                                                 int* __restrict__ tidx) {
    int r = blockIdx.x, t = threadIdx.x;
    int cg = t >> 5, l32 = t & 31;          // 8 groups of 32 lanes
    int c = cands[r * NCAND + cg];
    const float* Trow = T + (size_t)c * D_;
    const float* srow = s + (size_t)r * D_;
    float p = 0.f;
#pragma unroll
    for (int j = 0; j < 8; ++j) {
        int e = (j * 32 + l32) * 4;
        float4 a = *(const float4*)(srow + e);
        float4 b = *(const float4*)(Trow + e);
        p += a.x * b.x + a.y * b.y + a.z * b.z + a.w * b.w;
    }
#pragma unroll
    for (int off = 16; off >= 1; off >>= 1) p += __shfl_xor(p, off);  // stays in 32-group
    __shared__ float sc[NCAND];
    if (l32 == 0) sc[cg] = p;
    __syncthreads();
    if (t == 0) {
        float ip = invp[r];
        float b1 = NEG_INF, b2 = NEG_INF;
        int i1 = 0x7fffffff, i2 = 0x7fffffff;
#pragma unroll
        for (int j = 0; j < NCAND; ++j) {
            int ci = cands[r * NCAND + j];
            float val = sc[j] * invw[ci] * ip;
            if (better(val, ci, b1, i1)) { b2 = b1; i2 = i1; b1 = val; i1 = ci; }
            else if (better(val, ci, b2, i2)) { b2 = val; i2 = ci; }
        }
        outv[(size_t)r * 2 + 0] = b1;
        outv[(size_t)r * 2 + 1] = b2;
        tidx[r * 2 + 0] = i1;
        tidx[r * 2 + 1] = i2;
    }
}

// ---------------------------------------------------------------------------
// Kernel F: Z[r, 0:2, :] = T[idx], Z[r, 2:6, :] = P[r, :, :]
// ---------------------------------------------------------------------------
__global__ __launch_bounds__(256) void k_writeZ(const float* __restrict__ P,
                                                const float* __restrict__ T,
                                                const int* __restrict__ tidx,
                                                float* __restrict__ out) {
    int blk = blockIdx.x;  // r*6 + j
    int r = blk / 6, j = blk - r * 6;
    const float* src;
    if (j < KTOP) src = T + (size_t)tidx[r * 2 + j] * D_;
    else          src = P + ((size_t)r * NP_ + (j - KTOP)) * D_;
    float4 v = *(const float4*)(src + threadIdx.x * 4);
    *(float4*)(out + ((size_t)r * 6 + j) * D_ + threadIdx.x * 4) = v;
}

// ---------------------------------------------------------------------------
extern "C" void kernel_launch(void* const* d_in, const int* in_sizes, int n_in,
                              void* d_out, int out_size, void* d_ws, size_t ws_size,
                              hipStream_t stream) {
    const float* P   = (const float*)d_in[0];  // [32,64,4,1024]
    const float* we  = (const float*)d_in[1];  // [1024,768]
    const float* few = (const float*)d_in[2];  // [32000,768]
    const float* feb = (const float*)d_in[3];  // [32000]
    float* out = (float*)d_out;                // Z (12,582,912) then values (4096)
    float* ws  = (float*)d_ws;

    float* T    = ws + T_OFF;
    float* s    = ws + S_OFF;
    float* invw = ws + INVW_OFF;
    float* invp = ws + INVP_OFF;
    float* wsq  = ws + WSQ_OFF;
    float* pval = ws + PV_OFF;
    int*   pidx = (int*)(ws + PI_OFF);
    unsigned short* sb  = (unsigned short*)(ws + SB_OFF);
    unsigned short* Tb  = (unsigned short*)(ws + TB_OFF);
    unsigned short* weh = (unsigned short*)(ws + WH_OFF);
    unsigned short* wel = (unsigned short*)(ws + WL_OFF);
    int*   cands = (int*)(ws + CAND_OFF);
    int*   tidx  = (int*)(ws + TIDX_OFF);
    float* outv = out + (size_t)R_ * 6 * D_;

    k_zero<<<(VC_ + 255) / 256, 256, 0, stream>>>(wsq);
    k_split_we<<<(D_ * E_) / 1024, 256, 0, stream>>>(we, weh, wel);
    k_sum_pnorm<<<R_, 256, 0, stream>>>(P, s, sb, invp);
    k_gemm_T_mfma<<<dim3(D_ / 128, VC_ / 128), 256, 0, stream>>>(few, weh, wel, feb, T, Tb, wsq);
    k_invw<<<(VC_ + 255) / 256, 256, 0, stream>>>(wsq, invw);
    k_scores_mfma<<<dim3(VC_ / 128, R_ / 128), 256, 0, stream>>>(Tb, sb, invw, pval, pidx);
    k_topk8<<<R_, 256, 0, stream>>>(pval, pidx, cands);
    k_rescore<<<R_, 256, 0, stream>>>(s, T, cands, invw, invp, outv, tidx);
    k_writeZ<<<R_ * 6, 256, 0, stream>>>(P, T, tidx, out);
}

// Round 2
// 710.461 us; speedup vs baseline: 1.0317x; 1.0317x over previous
//
#include <hip/hip_runtime.h>
#include <hip/hip_bf16.h>
#include <math.h>

// Problem constants
#define B_    32
#define DIM_  64
#define NP_   4
#define D_    1024
#define E_    768
#define VC_   32000
#define R_    2048          // B_*DIM_
#define KTOP  2
#define EPS_  1e-8f
#define NCB   250           // 32000 / 128 v-blocks in scores GEMM
#define NCAND 8

// Workspace layout (float offsets), ~221 MB total
#define T_OFF    ((size_t)0)
#define S_OFF    (T_OFF + (size_t)VC_ * D_)          // 32,768,000
#define INVW_OFF (S_OFF + (size_t)R_ * D_)           // 34,865,152
#define INVP_OFF (INVW_OFF + VC_)
#define WSQ_OFF  (INVP_OFF + R_)
#define PV_OFF   (WSQ_OFF + VC_)
#define PI_OFF   (PV_OFF + (size_t)R_ * NCB * 2)
#define SB_OFF   (PI_OFF + (size_t)R_ * NCB * 2)     // ushort region, R_*D_ ushorts
#define TB_OFF   (SB_OFF + (size_t)R_ * D_ / 2)      // ushort region, VC_*D_ ushorts
#define WH_OFF   (TB_OFF + (size_t)VC_ * D_ / 2)     // ushort region, D_*E_ ushorts
#define WL_OFF   (WH_OFF + (size_t)D_ * E_ / 2)
#define CAND_OFF (WL_OFF + (size_t)D_ * E_ / 2)
#define TIDX_OFF (CAND_OFF + (size_t)R_ * NCAND)

#define NEG_INF (-3.4e38f)

typedef __bf16 bf16x8 __attribute__((ext_vector_type(8)));
typedef unsigned short u16x8 __attribute__((ext_vector_type(8)));
typedef float  f32x4  __attribute__((ext_vector_type(4)));

__device__ __forceinline__ unsigned short f2bf(float f) {
    unsigned u = __float_as_uint(f);
    u += 0x7fffu + ((u >> 16) & 1u);           // round-to-nearest-even
    return (unsigned short)(u >> 16);
}

// global -> LDS direct copy, 16B per lane. LDS dest = wave-uniform base + lane*16.
__device__ __forceinline__ void async_ld16(const void* gptr, void* lptr) {
    __builtin_amdgcn_global_load_lds(
        (const __attribute__((address_space(1))) void*)(uintptr_t)gptr,
        (__attribute__((address_space(3))) void*)(unsigned)(uintptr_t)lptr,
        16, 0, 0);
}

__device__ __forceinline__ bool better(float v, int i, float bv, int bi) {
    return (v > bv) || (v == bv && i < bi);
}

// ---------------------------------------------------------------------------
// Kernel Z0: zero the wsq accumulator (ws is poisoned before every launch)
// ---------------------------------------------------------------------------
__global__ __launch_bounds__(256) void k_zero(float* __restrict__ wsq) {
    int i = blockIdx.x * 256 + threadIdx.x;
    if (i < VC_) wsq[i] = 0.f;
}

// ---------------------------------------------------------------------------
// Kernel S0: split we (fp32 [D,E]) into bf16 hi/lo
// ---------------------------------------------------------------------------
__global__ __launch_bounds__(256) void k_split_we(const float* __restrict__ x,
                                                  unsigned short* __restrict__ hi,
                                                  unsigned short* __restrict__ lo) {
    int i = (blockIdx.x * 256 + threadIdx.x) * 4;   // grid sized exactly: D_*E_/1024 blocks
    float4 v = *(const float4*)(x + i);
    ushort4 h, l;
    float e;
    h.x = f2bf(v.x); e = v.x - __uint_as_float((unsigned)h.x << 16); l.x = f2bf(e);
    h.y = f2bf(v.y); e = v.y - __uint_as_float((unsigned)h.y << 16); l.y = f2bf(e);
    h.z = f2bf(v.z); e = v.z - __uint_as_float((unsigned)h.z << 16); l.z = f2bf(e);
    h.w = f2bf(v.w); e = v.w - __uint_as_float((unsigned)h.w << 16); l.w = f2bf(e);
    *(ushort4*)(hi + i) = h;
    *(ushort4*)(lo + i) = l;
}

// ---------------------------------------------------------------------------
// Kernel A: s[r,d] = sum_np P[r,np,d]; sb = bf16(s); invp[r] = 1/max(||P_r||,eps)
// ---------------------------------------------------------------------------
__global__ __launch_bounds__(256) void k_sum_pnorm(const float* __restrict__ P,
                                                   float* __restrict__ s,
                                                   unsigned short* __restrict__ sb,
                                                   float* __restrict__ invp) {
    int r = blockIdx.x;
    int t = threadIdx.x;
    const float* base = P + (size_t)r * NP_ * D_;
    float4 acc = make_float4(0.f, 0.f, 0.f, 0.f);
    float sq = 0.f;
#pragma unroll
    for (int np = 0; np < NP_; ++np) {
        float4 v = *(const float4*)(base + (size_t)np * D_ + t * 4);
        acc.x += v.x; acc.y += v.y; acc.z += v.z; acc.w += v.w;
        sq += v.x * v.x + v.y * v.y + v.z * v.z + v.w * v.w;
    }
    *(float4*)(s + (size_t)r * D_ + t * 4) = acc;
    ushort4 o;
    o.x = f2bf(acc.x); o.y = f2bf(acc.y); o.z = f2bf(acc.z); o.w = f2bf(acc.w);
    *(ushort4*)(sb + (size_t)r * D_ + t * 4) = o;

    __shared__ float red[256];
    red[t] = sq;
    __syncthreads();
    for (int off = 128; off > 0; off >>= 1) {
        if (t < off) red[t] += red[t + off];
        __syncthreads();
    }
    if (t == 0) invp[r] = 1.0f / fmaxf(sqrtf(red[0]), EPS_);
}

// ---------------------------------------------------------------------------
// Kernel B: split-bf16 MFMA GEMM.
//   T[v,d] = dot(few[v,:], we[d,:]) + bias[v]  via  Ah*Bh + Al*Bh + Ah*Bl
// A (few) staged fp32 via global_load_lds, split to hi/lo fragments in-register
// using NATIVE __bf16 casts (v_cvt_pk_bf16_f32 HW path, RNE — same semantics as
// the manual f2bf bit-trick but ~3x fewer VALU ops).
// B (we) pre-split bf16 hi/lo. Epilogue writes T (fp32), Tb (bf16) and
// accumulates per-row sumsq into wsq via atomics.
// Tile 128(v) x 128(d), BK=32, 4 waves.
// ---------------------------------------------------------------------------
__global__ __launch_bounds__(256) void k_gemm_T_mfma(const float* __restrict__ A,      // few [VC,E]
                                                     const unsigned short* __restrict__ Bh, // weh [D,E]
                                                     const unsigned short* __restrict__ Bl, // wel [D,E]
                                                     const float* __restrict__ bias,
                                                     float* __restrict__ T,
                                                     unsigned short* __restrict__ Tb,
                                                     float* __restrict__ wsq) {
    __shared__ __align__(16) float          Af[128 * 32];   // 16 KB, [v-row][k] fp32
    __shared__ __align__(16) unsigned short Bsh[128 * 32];  //  8 KB
    __shared__ __align__(16) unsigned short Bsl[128 * 32];  //  8 KB

    int tid = threadIdx.x;
    int wid = tid >> 6, lane = tid & 63;
    int quad = lane >> 4, l15 = lane & 15;
    int v0 = blockIdx.y * 128;
    int d0 = blockIdx.x * 128;
    int vband = (wid & 1) * 64, nband = (wid >> 1) * 64;

    f32x4 acc[4][4];
#pragma unroll
    for (int i = 0; i < 4; ++i)
#pragma unroll
        for (int j = 0; j < 4; ++j) acc[i][j] = f32x4{0.f, 0.f, 0.f, 0.f};

    int arow = wid * 32 + (lane >> 3);   // fp32 staging: 8 rows per wave-issue
    int acol = (lane & 7) * 4;           // float offset (16 B)
    int brow = wid * 32 + (lane >> 2);   // bf16 staging: 16 rows per wave-issue
    int bcol = (lane & 3) * 8;           // ushort offset (16 B)

    for (int k0 = 0; k0 < E_; k0 += 32) {
#pragma unroll
        for (int j = 0; j < 4; ++j)
            async_ld16(A + (size_t)(v0 + arow + j * 8) * E_ + k0 + acol,
                       (void*)(Af + (wid * 32 + j * 8) * 32));
#pragma unroll
        for (int j = 0; j < 2; ++j) {
            async_ld16(Bh + (size_t)(d0 + brow + j * 16) * E_ + k0 + bcol,
                       (void*)(Bsh + (wid * 32 + j * 16) * 32));
            async_ld16(Bl + (size_t)(d0 + brow + j * 16) * E_ + k0 + bcol,
                       (void*)(Bsl + (wid * 32 + j * 16) * 32));
        }
        __syncthreads();

        bf16x8 bh[4], bl[4];
#pragma unroll
        for (int nt = 0; nt < 4; ++nt) {
            bh[nt] = *(const bf16x8*)(Bsh + (nband + nt * 16 + l15) * 32 + quad * 8);
            bl[nt] = *(const bf16x8*)(Bsl + (nband + nt * 16 + l15) * 32 + quad * 8);
        }
#pragma unroll
        for (int mt = 0; mt < 4; ++mt) {
            const float* ap = Af + (vband + mt * 16 + l15) * 32 + quad * 8;
            f32x4 xa = *(const f32x4*)ap;
            f32x4 xb = *(const f32x4*)(ap + 4);
            bf16x8 ah, al;
#pragma unroll
            for (int e = 0; e < 4; ++e) {
                __bf16 h0 = (__bf16)xa[e];          // native RNE cvt
                __bf16 h1 = (__bf16)xb[e];
                ah[e] = h0; ah[e + 4] = h1;
                al[e]     = (__bf16)(xa[e] - (float)h0);
                al[e + 4] = (__bf16)(xb[e] - (float)h1);
            }
#pragma unroll
            for (int nt = 0; nt < 4; ++nt) {
                acc[mt][nt] = __builtin_amdgcn_mfma_f32_16x16x32_bf16(ah, bh[nt], acc[mt][nt], 0, 0, 0);
                acc[mt][nt] = __builtin_amdgcn_mfma_f32_16x16x32_bf16(al, bh[nt], acc[mt][nt], 0, 0, 0);
                acc[mt][nt] = __builtin_amdgcn_mfma_f32_16x16x32_bf16(ah, bl[nt], acc[mt][nt], 0, 0, 0);
            }
        }
        __syncthreads();
    }

    // Epilogue: T fp32, Tb bf16, row-sumsq partials -> wsq atomics
    float sq[4][4] = {};
#pragma unroll
    for (int mt = 0; mt < 4; ++mt) {
        int vbase = v0 + vband + mt * 16 + quad * 4;
        float bv[4];
#pragma unroll
        for (int rg = 0; rg < 4; ++rg) bv[rg] = bias[vbase + rg];
#pragma unroll
        for (int nt = 0; nt < 4; ++nt) {
            int d = d0 + nband + nt * 16 + l15;
#pragma unroll
            for (int rg = 0; rg < 4; ++rg) {
                float val = acc[mt][nt][rg] + bv[rg];
                T[(size_t)(vbase + rg) * D_ + d] = val;
                __bf16 vb = (__bf16)val;
                Tb[(size_t)(vbase + rg) * D_ + d] = __builtin_bit_cast(unsigned short, vb);
                sq[mt][rg] += val * val;
            }
        }
    }
#pragma unroll
    for (int mt = 0; mt < 4; ++mt)
#pragma unroll
        for (int rg = 0; rg < 4; ++rg) {
            float p = sq[mt][rg];
            p += __shfl_xor(p, 1); p += __shfl_xor(p, 2);
            p += __shfl_xor(p, 4); p += __shfl_xor(p, 8);
            if (l15 == 0) atomicAdd(&wsq[v0 + vband + mt * 16 + quad * 4 + rg], p);
        }
}

// ---------------------------------------------------------------------------
// Kernel W: invw[v] = 1 / max(2*sqrt(wsq[v]), eps)
// ---------------------------------------------------------------------------
__global__ __launch_bounds__(256) void k_invw(const float* __restrict__ wsq,
                                              float* __restrict__ invw) {
    int v = blockIdx.x * 256 + threadIdx.x;
    if (v < VC_) invw[v] = 1.0f / fmaxf(2.0f * sqrtf(wsq[v]), EPS_);
}

// ---------------------------------------------------------------------------
// Kernel C: bf16 MFMA candidate GEMM. Tile 128(v) x 128(r), BK=32.
// Tb is UNSCALED bf16(T); invw applied in the epilogue before ranking.
// Emits per-(r, v-block) top-2 partials (approx values, used only to nominate).
// ---------------------------------------------------------------------------
__global__ __launch_bounds__(256) void k_scores_mfma(const unsigned short* __restrict__ Tb,
                                                     const unsigned short* __restrict__ sb,
                                                     const float* __restrict__ invw,
                                                     float* __restrict__ pval,
                                                     int* __restrict__ pidx) {
    __shared__ __align__(16) unsigned short As[128 * 32];  // [v-row][k]
    __shared__ __align__(16) unsigned short Bs[128 * 32];  // [r-row][k]
    __shared__ float mv[2][128][2];
    __shared__ int   mi[2][128][2];

    int tid = threadIdx.x;
    int wid = tid >> 6, lane = tid & 63;
    int quad = lane >> 4, l15 = lane & 15;
    int v0 = blockIdx.x * 128;
    int r0 = blockIdx.y * 128;
    int vband = (wid & 1) * 64, rband = (wid >> 1) * 64;

    f32x4 acc[4][4];
#pragma unroll
    for (int i = 0; i < 4; ++i)
#pragma unroll
        for (int j = 0; j < 4; ++j) acc[i][j] = f32x4{0.f, 0.f, 0.f, 0.f};

    int srow  = wid * 32 + (lane >> 2);
    int skoff = (lane & 3) * 8;

    for (int k0 = 0; k0 < D_; k0 += 32) {
#pragma unroll
        for (int j = 0; j < 2; ++j) {
            async_ld16(Tb + (size_t)(v0 + srow + j * 16) * D_ + k0 + skoff,
                       (void*)(As + (wid * 32 + j * 16) * 32));
            async_ld16(sb + (size_t)(r0 + srow + j * 16) * D_ + k0 + skoff,
                       (void*)(Bs + (wid * 32 + j * 16) * 32));
        }
        __syncthreads();
        bf16x8 af[4], bf[4];
#pragma unroll
        for (int mt = 0; mt < 4; ++mt)
            af[mt] = *(const bf16x8*)(As + (vband + mt * 16 + l15) * 32 + quad * 8);
#pragma unroll
        for (int nt = 0; nt < 4; ++nt)
            bf[nt] = *(const bf16x8*)(Bs + (rband + nt * 16 + l15) * 32 + quad * 8);
#pragma unroll
        for (int mt = 0; mt < 4; ++mt)
#pragma unroll
            for (int nt = 0; nt < 4; ++nt)
                acc[mt][nt] = __builtin_amdgcn_mfma_f32_16x16x32_bf16(af[mt], bf[nt], acc[mt][nt], 0, 0, 0);
        __syncthreads();
    }

    // Epilogue: scale by invw[v], per r top-2 over this block's 128 v's.
    float iw[4][4];
#pragma unroll
    for (int mt = 0; mt < 4; ++mt)
#pragma unroll
        for (int rg = 0; rg < 4; ++rg)
            iw[mt][rg] = invw[v0 + vband + mt * 16 + quad * 4 + rg];

#pragma unroll
    for (int nt = 0; nt < 4; ++nt) {
        float b1 = NEG_INF, b2 = NEG_INF;
        int i1 = 0x7fffffff, i2 = 0x7fffffff;
#pragma unroll
        for (int mt = 0; mt < 4; ++mt)
#pragma unroll
            for (int rg = 0; rg < 4; ++rg) {
                float val = acc[mt][nt][rg] * iw[mt][rg];
                int v = v0 + vband + mt * 16 + quad * 4 + rg;
                if (better(val, v, b1, i1)) { b2 = b1; i2 = i1; b1 = val; i1 = v; }
                else if (better(val, v, b2, i2)) { b2 = val; i2 = v; }
            }
#pragma unroll
        for (int off = 16; off <= 32; off <<= 1) {
            float o1 = __shfl_xor(b1, off), o2 = __shfl_xor(b2, off);
            int  oi1 = __shfl_xor(i1, off), oi2 = __shfl_xor(i2, off);
            if (better(o1, oi1, b1, i1)) {
                if (better(b1, i1, o2, oi2)) { b2 = b1; i2 = i1; } else { b2 = o2; i2 = oi2; }
                b1 = o1; i1 = oi1;
            } else if (better(o1, oi1, b2, i2)) { b2 = o1; i2 = oi1; }
        }
        if (quad == 0) {
            int rl = rband + nt * 16 + l15;
            mv[wid & 1][rl][0] = b1; mi[wid & 1][rl][0] = i1;
            mv[wid & 1][rl][1] = b2; mi[wid & 1][rl][1] = i2;
        }
    }
    __syncthreads();
    if (tid < 128) {
        float b1 = mv[0][tid][0], b2 = mv[0][tid][1];
        int   i1 = mi[0][tid][0], i2 = mi[0][tid][1];
#pragma unroll
        for (int sl = 0; sl < 2; ++sl) {
            float o = mv[1][tid][sl]; int oi = mi[1][tid][sl];
            if (better(o, oi, b1, i1)) { b2 = b1; i2 = i1; b1 = o; i1 = oi; }
            else if (better(o, oi, b2, i2)) { b2 = o; i2 = oi; }
        }
        size_t off = ((size_t)(r0 + tid) * NCB + blockIdx.x) * 2;
        pval[off] = b1;     pidx[off] = i1;
        pval[off + 1] = b2; pidx[off + 1] = i2;
    }
}

// ---------------------------------------------------------------------------
// Kernel D: top-8 candidates per row from the 500 partials (approx ranking)
// ---------------------------------------------------------------------------
__global__ __launch_bounds__(256) void k_topk8(const float* __restrict__ pval,
                                               const int* __restrict__ pidx,
                                               int* __restrict__ cands) {
    int r = blockIdx.x, t = threadIdx.x;
    __shared__ float v[512];
    __shared__ int  id[512];
    for (int c = t; c < 512; c += 256) {
        if (c < NCB * 2) { v[c] = pval[(size_t)r * NCB * 2 + c]; id[c] = pidx[(size_t)r * NCB * 2 + c]; }
        else             { v[c] = NEG_INF; id[c] = 0x7fffffff; }
    }
    __syncthreads();
    if (t == 0) {
        float bv[NCAND]; int bi[NCAND];
#pragma unroll
        for (int j = 0; j < NCAND; ++j) { bv[j] = NEG_INF; bi[j] = 0x7fffffff; }
        for (int c = 0; c < NCB * 2; ++c) {
            float x = v[c]; int xi = id[c];
            if (better(x, xi, bv[NCAND - 1], bi[NCAND - 1])) {
                int j = NCAND - 1;
                while (j > 0 && better(x, xi, bv[j - 1], bi[j - 1])) {
                    bv[j] = bv[j - 1]; bi[j] = bi[j - 1]; --j;
                }
                bv[j] = x; bi[j] = xi;
            }
        }
#pragma unroll
        for (int j = 0; j < NCAND; ++j) cands[r * NCAND + j] = bi[j];
    }
}

// ---------------------------------------------------------------------------
// Kernel E: exact fp32 rescore of 8 candidates/row -> final top-2 + values
// ---------------------------------------------------------------------------
__global__ __launch_bounds__(256) void k_rescore(const float* __restrict__ s,
                                                 const float* __restrict__ T,
                                                 const int* __restrict__ cands,
                                                 const float* __restrict__ invw,
                                                 const float* __restrict__ invp,
                                                 float* __restrict__ outv,
                                                 int* __restrict__ tidx) {
    int r = blockIdx.x, t = threadIdx.x;
    int cg = t >> 5, l32 = t & 31;          // 8 groups of 32 lanes
    int c = cands[r * NCAND + cg];
    const float* Trow = T + (size_t)c * D_;
    const float* srow = s + (size_t)r * D_;
    float p = 0.f;
#pragma unroll
    for (int j = 0; j < 8; ++j) {
        int e = (j * 32 + l32) * 4;
        float4 a = *(const float4*)(srow + e);
        float4 b = *(const float4*)(Trow + e);
        p += a.x * b.x + a.y * b.y + a.z * b.z + a.w * b.w;
    }
#pragma unroll
    for (int off = 16; off >= 1; off >>= 1) p += __shfl_xor(p, off);  // stays in 32-group
    __shared__ float sc[NCAND];
    if (l32 == 0) sc[cg] = p;
    __syncthreads();
    if (t == 0) {
        float ip = invp[r];
        float b1 = NEG_INF, b2 = NEG_INF;
        int i1 = 0x7fffffff, i2 = 0x7fffffff;
#pragma unroll
        for (int j = 0; j < NCAND; ++j) {
            int ci = cands[r * NCAND + j];
            float val = sc[j] * invw[ci] * ip;
            if (better(val, ci, b1, i1)) { b2 = b1; i2 = i1; b1 = val; i1 = ci; }
            else if (better(val, ci, b2, i2)) { b2 = val; i2 = ci; }
        }
        outv[(size_t)r * 2 + 0] = b1;
        outv[(size_t)r * 2 + 1] = b2;
        tidx[r * 2 + 0] = i1;
        tidx[r * 2 + 1] = i2;
    }
}

// ---------------------------------------------------------------------------
// Kernel F: Z[r, 0:2, :] = T[idx], Z[r, 2:6, :] = P[r, :, :]
// ---------------------------------------------------------------------------
__global__ __launch_bounds__(256) void k_writeZ(const float* __restrict__ P,
                                                const float* __restrict__ T,
                                                const int* __restrict__ tidx,
                                                float* __restrict__ out) {
    int blk = blockIdx.x;  // r*6 + j
    int r = blk / 6, j = blk - r * 6;
    const float* src;
    if (j < KTOP) src = T + (size_t)tidx[r * 2 + j] * D_;
    else          src = P + ((size_t)r * NP_ + (j - KTOP)) * D_;
    float4 v = *(const float4*)(src + threadIdx.x * 4);
    *(float4*)(out + ((size_t)r * 6 + j) * D_ + threadIdx.x * 4) = v;
}

// ---------------------------------------------------------------------------
extern "C" void kernel_launch(void* const* d_in, const int* in_sizes, int n_in,
                              void* d_out, int out_size, void* d_ws, size_t ws_size,
                              hipStream_t stream) {
    const float* P   = (const float*)d_in[0];  // [32,64,4,1024]
    const float* we  = (const float*)d_in[1];  // [1024,768]
    const float* few = (const float*)d_in[2];  // [32000,768]
    const float* feb = (const float*)d_in[3];  // [32000]
    float* out = (float*)d_out;                // Z (12,582,912) then values (4096)
    float* ws  = (float*)d_ws;

    float* T    = ws + T_OFF;
    float* s    = ws + S_OFF;
    float* invw = ws + INVW_OFF;
    float* invp = ws + INVP_OFF;
    float* wsq  = ws + WSQ_OFF;
    float* pval = ws + PV_OFF;
    int*   pidx = (int*)(ws + PI_OFF);
    unsigned short* sb  = (unsigned short*)(ws + SB_OFF);
    unsigned short* Tb  = (unsigned short*)(ws + TB_OFF);
    unsigned short* weh = (unsigned short*)(ws + WH_OFF);
    unsigned short* wel = (unsigned short*)(ws + WL_OFF);
    int*   cands = (int*)(ws + CAND_OFF);
    int*   tidx  = (int*)(ws + TIDX_OFF);
    float* outv = out + (size_t)R_ * 6 * D_;

    k_zero<<<(VC_ + 255) / 256, 256, 0, stream>>>(wsq);
    k_split_we<<<(D_ * E_) / 1024, 256, 0, stream>>>(we, weh, wel);
    k_sum_pnorm<<<R_, 256, 0, stream>>>(P, s, sb, invp);
    k_gemm_T_mfma<<<dim3(D_ / 128, VC_ / 128), 256, 0, stream>>>(few, weh, wel, feb, T, Tb, wsq);
    k_invw<<<(VC_ + 255) / 256, 256, 0, stream>>>(wsq, invw);
    k_scores_mfma<<<dim3(VC_ / 128, R_ / 128), 256, 0, stream>>>(Tb, sb, invw, pval, pidx);
    k_topk8<<<R_, 256, 0, stream>>>(pval, pidx, cands);
    k_rescore<<<R_, 256, 0, stream>>>(s, T, cands, invw, invp, outv, tidx);
    k_writeZ<<<R_ * 6, 256, 0, stream>>>(P, T, tidx, out);
}

// Round 3
// 683.072 us; speedup vs baseline: 1.0730x; 1.0401x over previous
//
#include <hip/hip_runtime.h>
#include <hip/hip_bf16.h>
#include <math.h>

// Problem constants
#define B_    32
#define DIM_  64
#define NP_   4
#define D_    1024
#define E_    768
#define VC_   32000
#define R_    2048          // B_*DIM_
#define KTOP  2
#define EPS_  1e-8f
#define NCB   250           // 32000 / 128 v-blocks in scores GEMM
#define NCAND 8

// Workspace layout (float offsets), ~221 MB total
#define T_OFF    ((size_t)0)
#define S_OFF    (T_OFF + (size_t)VC_ * D_)          // 32,768,000
#define INVW_OFF (S_OFF + (size_t)R_ * D_)           // 34,865,152
#define INVP_OFF (INVW_OFF + VC_)
#define WSQ_OFF  (INVP_OFF + R_)
#define PV_OFF   (WSQ_OFF + VC_)
#define PI_OFF   (PV_OFF + (size_t)R_ * NCB * 2)
#define SB_OFF   (PI_OFF + (size_t)R_ * NCB * 2)     // ushort region, R_*D_ ushorts
#define TB_OFF   (SB_OFF + (size_t)R_ * D_ / 2)      // ushort region, VC_*D_ ushorts
#define WH_OFF   (TB_OFF + (size_t)VC_ * D_ / 2)     // ushort region, D_*E_ ushorts
#define WL_OFF   (WH_OFF + (size_t)D_ * E_ / 2)
#define CAND_OFF (WL_OFF + (size_t)D_ * E_ / 2)
#define TIDX_OFF (CAND_OFF + (size_t)R_ * NCAND)

#define NEG_INF (-3.4e38f)

typedef __bf16 bf16x8 __attribute__((ext_vector_type(8)));
typedef unsigned short u16x8 __attribute__((ext_vector_type(8)));
typedef float  f32x4  __attribute__((ext_vector_type(4)));

__device__ __forceinline__ unsigned short f2bf(float f) {
    unsigned u = __float_as_uint(f);
    u += 0x7fffu + ((u >> 16) & 1u);           // round-to-nearest-even
    return (unsigned short)(u >> 16);
}

// global -> LDS direct copy, 16B per lane. LDS dest = wave-uniform base + lane*16.
__device__ __forceinline__ void async_ld16(const void* gptr, void* lptr) {
    __builtin_amdgcn_global_load_lds(
        (const __attribute__((address_space(1))) void*)(uintptr_t)gptr,
        (__attribute__((address_space(3))) void*)(unsigned)(uintptr_t)lptr,
        16, 0, 0);
}

__device__ __forceinline__ bool better(float v, int i, float bv, int bi) {
    return (v > bv) || (v == bv && i < bi);
}

// ---------------------------------------------------------------------------
// Kernel Z0: zero the wsq accumulator (ws is poisoned before every launch)
// ---------------------------------------------------------------------------
__global__ __launch_bounds__(256) void k_zero(float* __restrict__ wsq) {
    int i = blockIdx.x * 256 + threadIdx.x;
    if (i < VC_) wsq[i] = 0.f;
}

// ---------------------------------------------------------------------------
// Kernel S0: split we (fp32 [D,E]) into bf16 hi/lo
// ---------------------------------------------------------------------------
__global__ __launch_bounds__(256) void k_split_we(const float* __restrict__ x,
                                                  unsigned short* __restrict__ hi,
                                                  unsigned short* __restrict__ lo) {
    int i = (blockIdx.x * 256 + threadIdx.x) * 4;   // grid sized exactly: D_*E_/1024 blocks
    float4 v = *(const float4*)(x + i);
    ushort4 h, l;
    float e;
    h.x = f2bf(v.x); e = v.x - __uint_as_float((unsigned)h.x << 16); l.x = f2bf(e);
    h.y = f2bf(v.y); e = v.y - __uint_as_float((unsigned)h.y << 16); l.y = f2bf(e);
    h.z = f2bf(v.z); e = v.z - __uint_as_float((unsigned)h.z << 16); l.z = f2bf(e);
    h.w = f2bf(v.w); e = v.w - __uint_as_float((unsigned)h.w << 16); l.w = f2bf(e);
    *(ushort4*)(hi + i) = h;
    *(ushort4*)(lo + i) = l;
}

// ---------------------------------------------------------------------------
// Kernel A: s[r,d] = sum_np P[r,np,d]; sb = bf16(s); invp[r] = 1/max(||P_r||,eps)
// ---------------------------------------------------------------------------
__global__ __launch_bounds__(256) void k_sum_pnorm(const float* __restrict__ P,
                                                   float* __restrict__ s,
                                                   unsigned short* __restrict__ sb,
                                                   float* __restrict__ invp) {
    int r = blockIdx.x;
    int t = threadIdx.x;
    const float* base = P + (size_t)r * NP_ * D_;
    float4 acc = make_float4(0.f, 0.f, 0.f, 0.f);
    float sq = 0.f;
#pragma unroll
    for (int np = 0; np < NP_; ++np) {
        float4 v = *(const float4*)(base + (size_t)np * D_ + t * 4);
        acc.x += v.x; acc.y += v.y; acc.z += v.z; acc.w += v.w;
        sq += v.x * v.x + v.y * v.y + v.z * v.z + v.w * v.w;
    }
    *(float4*)(s + (size_t)r * D_ + t * 4) = acc;
    ushort4 o;
    o.x = f2bf(acc.x); o.y = f2bf(acc.y); o.z = f2bf(acc.z); o.w = f2bf(acc.w);
    *(ushort4*)(sb + (size_t)r * D_ + t * 4) = o;

    __shared__ float red[256];
    red[t] = sq;
    __syncthreads();
    for (int off = 128; off > 0; off >>= 1) {
        if (t < off) red[t] += red[t + off];
        __syncthreads();
    }
    if (t == 0) invp[r] = 1.0f / fmaxf(sqrtf(red[0]), EPS_);
}

// ---------------------------------------------------------------------------
// Kernel B: split-bf16 MFMA GEMM.
//   T[v,d] = dot(few[v,:], we[d,:]) + bias[v]  via  Ah*Bh + Al*Bh + Ah*Bl
// A (few) staged fp32 via global_load_lds, split hi/lo in-register (native cvt).
// Grid: 1-D 2000 blocks, XCD-chunked swizzle (T1), v-major so the 8 d-blocks of
// one few-panel run on one XCD (panel fetched ~once per XCD).
// Tile 128(v) x 128(d), BK=32, 4 waves.
// ---------------------------------------------------------------------------
__global__ __launch_bounds__(256) void k_gemm_T_mfma(const float* __restrict__ A,      // few [VC,E]
                                                     const unsigned short* __restrict__ Bh, // weh [D,E]
                                                     const unsigned short* __restrict__ Bl, // wel [D,E]
                                                     const float* __restrict__ bias,
                                                     float* __restrict__ T,
                                                     unsigned short* __restrict__ Tb,
                                                     float* __restrict__ wsq) {
    __shared__ __align__(16) float          Af[128 * 32];   // 16 KB, [v-row][k] fp32
    __shared__ __align__(16) unsigned short Bsh[128 * 32];  //  8 KB
    __shared__ __align__(16) unsigned short Bsl[128 * 32];  //  8 KB

    int tid = threadIdx.x;
    int wid = tid >> 6, lane = tid & 63;
    int quad = lane >> 4, l15 = lane & 15;
    // T1: XCD-chunked swizzle. nwg=2000, 8 XCDs, 250/chunk. v-major decompose.
    int id  = blockIdx.x;
    int swz = (id & 7) * 250 + (id >> 3);
    int v0 = (swz >> 3) * 128;     // 250 v-panels
    int d0 = (swz & 7) * 128;      // 8 d-blocks per panel
    int vband = (wid & 1) * 64, nband = (wid >> 1) * 64;

    f32x4 acc[4][4];
#pragma unroll
    for (int i = 0; i < 4; ++i)
#pragma unroll
        for (int j = 0; j < 4; ++j) acc[i][j] = f32x4{0.f, 0.f, 0.f, 0.f};

    int arow = wid * 32 + (lane >> 3);   // fp32 staging: 8 rows per wave-issue
    int acol = (lane & 7) * 4;           // float offset (16 B)
    int brow = wid * 32 + (lane >> 2);   // bf16 staging: 16 rows per wave-issue
    int bcol = (lane & 3) * 8;           // ushort offset (16 B)

    for (int k0 = 0; k0 < E_; k0 += 32) {
#pragma unroll
        for (int j = 0; j < 4; ++j)
            async_ld16(A + (size_t)(v0 + arow + j * 8) * E_ + k0 + acol,
                       (void*)(Af + (wid * 32 + j * 8) * 32));
#pragma unroll
        for (int j = 0; j < 2; ++j) {
            async_ld16(Bh + (size_t)(d0 + brow + j * 16) * E_ + k0 + bcol,
                       (void*)(Bsh + (wid * 32 + j * 16) * 32));
            async_ld16(Bl + (size_t)(d0 + brow + j * 16) * E_ + k0 + bcol,
                       (void*)(Bsl + (wid * 32 + j * 16) * 32));
        }
        __syncthreads();

        bf16x8 bh[4], bl[4];
#pragma unroll
        for (int nt = 0; nt < 4; ++nt) {
            bh[nt] = *(const bf16x8*)(Bsh + (nband + nt * 16 + l15) * 32 + quad * 8);
            bl[nt] = *(const bf16x8*)(Bsl + (nband + nt * 16 + l15) * 32 + quad * 8);
        }
#pragma unroll
        for (int mt = 0; mt < 4; ++mt) {
            const float* ap = Af + (vband + mt * 16 + l15) * 32 + quad * 8;
            f32x4 xa = *(const f32x4*)ap;
            f32x4 xb = *(const f32x4*)(ap + 4);
            bf16x8 ah, al;
#pragma unroll
            for (int e = 0; e < 4; ++e) {
                __bf16 h0 = (__bf16)xa[e];          // native RNE cvt
                __bf16 h1 = (__bf16)xb[e];
                ah[e] = h0; ah[e + 4] = h1;
                al[e]     = (__bf16)(xa[e] - (float)h0);
                al[e + 4] = (__bf16)(xb[e] - (float)h1);
            }
#pragma unroll
            for (int nt = 0; nt < 4; ++nt) {
                acc[mt][nt] = __builtin_amdgcn_mfma_f32_16x16x32_bf16(ah, bh[nt], acc[mt][nt], 0, 0, 0);
                acc[mt][nt] = __builtin_amdgcn_mfma_f32_16x16x32_bf16(al, bh[nt], acc[mt][nt], 0, 0, 0);
                acc[mt][nt] = __builtin_amdgcn_mfma_f32_16x16x32_bf16(ah, bl[nt], acc[mt][nt], 0, 0, 0);
            }
        }
        __syncthreads();
    }

    // Epilogue: T fp32, Tb bf16, row-sumsq partials -> wsq atomics
    float sq[4][4] = {};
#pragma unroll
    for (int mt = 0; mt < 4; ++mt) {
        int vbase = v0 + vband + mt * 16 + quad * 4;
        float bv[4];
#pragma unroll
        for (int rg = 0; rg < 4; ++rg) bv[rg] = bias[vbase + rg];
#pragma unroll
        for (int nt = 0; nt < 4; ++nt) {
            int d = d0 + nband + nt * 16 + l15;
#pragma unroll
            for (int rg = 0; rg < 4; ++rg) {
                float val = acc[mt][nt][rg] + bv[rg];
                T[(size_t)(vbase + rg) * D_ + d] = val;
                __bf16 vb = (__bf16)val;
                Tb[(size_t)(vbase + rg) * D_ + d] = __builtin_bit_cast(unsigned short, vb);
                sq[mt][rg] += val * val;
            }
        }
    }
#pragma unroll
    for (int mt = 0; mt < 4; ++mt)
#pragma unroll
        for (int rg = 0; rg < 4; ++rg) {
            float p = sq[mt][rg];
            p += __shfl_xor(p, 1); p += __shfl_xor(p, 2);
            p += __shfl_xor(p, 4); p += __shfl_xor(p, 8);
            if (l15 == 0) atomicAdd(&wsq[v0 + vband + mt * 16 + quad * 4 + rg], p);
        }
}

// ---------------------------------------------------------------------------
// Kernel W: invw[v] = 1 / max(2*sqrt(wsq[v]), eps)
// ---------------------------------------------------------------------------
__global__ __launch_bounds__(256) void k_invw(const float* __restrict__ wsq,
                                              float* __restrict__ invw) {
    int v = blockIdx.x * 256 + threadIdx.x;
    if (v < VC_) invw[v] = 1.0f / fmaxf(2.0f * sqrtf(wsq[v]), EPS_);
}

// ---------------------------------------------------------------------------
// Kernel C: bf16 MFMA candidate GEMM. Tile 128(v) x 128(r), BK=32.
// v2: T3-minimum pipeline (double-buffered LDS, stage t+1 issued at loop top,
// ONE barrier per K-step so loads get a full compute window to land),
// bank-deconflict slot rotation (read slot' = (quad+(row>>1))&3, staging source
// pre-rotated by the inverse -> 2-way max, free), T1 XCD-chunked grid swizzle
// (16 r-blocks of one Tb panel stay on one XCD).
// ---------------------------------------------------------------------------
__global__ __launch_bounds__(256) void k_scores_mfma(const unsigned short* __restrict__ Tb,
                                                     const unsigned short* __restrict__ sb,
                                                     const float* __restrict__ invw,
                                                     float* __restrict__ pval,
                                                     int* __restrict__ pidx) {
    __shared__ __align__(16) unsigned short As[2][128 * 32];  // 2 x 8 KB, [v-row][k]
    __shared__ __align__(16) unsigned short Bs[2][128 * 32];  // 2 x 8 KB, [r-row][k]
    __shared__ float mv[2][128][2];
    __shared__ int   mi[2][128][2];

    int tid = threadIdx.x;
    int wid = tid >> 6, lane = tid & 63;
    int quad = lane >> 4, l15 = lane & 15;
    // T1: nwg=4000, 500/XCD-chunk, v-major decompose (16 r-blocks per panel).
    int id   = blockIdx.x;
    int swz  = (id & 7) * 500 + (id >> 3);
    int vblk = swz >> 4;               // 0..249
    int rblk = swz & 15;               // 0..15
    int v0 = vblk * 128;
    int r0 = rblk * 128;
    int vband = (wid & 1) * 64, rband = (wid >> 1) * 64;

    f32x4 acc[4][4];
#pragma unroll
    for (int i = 0; i < 4; ++i)
#pragma unroll
        for (int j = 0; j < 4; ++j) acc[i][j] = f32x4{0.f, 0.f, 0.f, 0.f};

    int r_lane = lane >> 2;            // staging row within 16-row group
    int slot   = lane & 3;             // which 16B slot this lane writes (linear LDS)

    // Stage K-tile kk into buffer buf. LDS dest is linear (wave base + lane*16);
    // source column pre-rotated so LDS(row, s) holds logical slot (s - (row>>1))&3.
#define STAGE_SC(buf, kk)                                                          \
    {                                                                              \
_Pragma("unroll")                                                                  \
        for (int j = 0; j < 2; ++j) {                                              \
            int rowt = wid * 32 + j * 16 + r_lane;                                 \
            int ss = (slot - (rowt >> 1)) & 3;                                     \
            async_ld16(Tb + (size_t)(v0 + rowt) * D_ + (kk) + ss * 8,              \
                       (void*)(As[buf] + (wid * 32 + j * 16) * 32));               \
            async_ld16(sb + (size_t)(r0 + rowt) * D_ + (kk) + ss * 8,              \
                       (void*)(Bs[buf] + (wid * 32 + j * 16) * 32));               \
        }                                                                          \
    }

    int cur = 0;
    STAGE_SC(0, 0);
    __syncthreads();                   // drain prologue stage (vmcnt(0) implied)

    for (int k0 = 0; k0 < D_; k0 += 32) {
        if (k0 + 32 < D_) STAGE_SC(cur ^ 1, k0 + 32);   // issue next tile EARLY

        bf16x8 af[4], bfr[4];
#pragma unroll
        for (int mt = 0; mt < 4; ++mt) {
            int row = vband + mt * 16 + l15;
            int ps = (quad + (row >> 1)) & 3;           // de-conflict rotation
            af[mt] = *(const bf16x8*)(As[cur] + row * 32 + ps * 8);
        }
#pragma unroll
        for (int nt = 0; nt < 4; ++nt) {
            int row = rband + nt * 16 + l15;
            int ps = (quad + (row >> 1)) & 3;
            bfr[nt] = *(const bf16x8*)(Bs[cur] + row * 32 + ps * 8);
        }
#pragma unroll
        for (int mt = 0; mt < 4; ++mt)
#pragma unroll
            for (int nt = 0; nt < 4; ++nt)
                acc[mt][nt] = __builtin_amdgcn_mfma_f32_16x16x32_bf16(af[mt], bfr[nt], acc[mt][nt], 0, 0, 0);

        __syncthreads();               // single barrier: drains next-tile loads
        cur ^= 1;
    }

    // Epilogue: scale by invw[v], per r top-2 over this block's 128 v's.
    float iw[4][4];
#pragma unroll
    for (int mt = 0; mt < 4; ++mt)
#pragma unroll
        for (int rg = 0; rg < 4; ++rg)
            iw[mt][rg] = invw[v0 + vband + mt * 16 + quad * 4 + rg];

#pragma unroll
    for (int nt = 0; nt < 4; ++nt) {
        float b1 = NEG_INF, b2 = NEG_INF;
        int i1 = 0x7fffffff, i2 = 0x7fffffff;
#pragma unroll
        for (int mt = 0; mt < 4; ++mt)
#pragma unroll
            for (int rg = 0; rg < 4; ++rg) {
                float val = acc[mt][nt][rg] * iw[mt][rg];
                int v = v0 + vband + mt * 16 + quad * 4 + rg;
                if (better(val, v, b1, i1)) { b2 = b1; i2 = i1; b1 = val; i1 = v; }
                else if (better(val, v, b2, i2)) { b2 = val; i2 = v; }
            }
#pragma unroll
        for (int off = 16; off <= 32; off <<= 1) {
            float o1 = __shfl_xor(b1, off), o2 = __shfl_xor(b2, off);
            int  oi1 = __shfl_xor(i1, off), oi2 = __shfl_xor(i2, off);
            if (better(o1, oi1, b1, i1)) {
                if (better(b1, i1, o2, oi2)) { b2 = b1; i2 = i1; } else { b2 = o2; i2 = oi2; }
                b1 = o1; i1 = oi1;
            } else if (better(o1, oi1, b2, i2)) { b2 = o1; i2 = oi1; }
        }
        if (quad == 0) {
            int rl = rband + nt * 16 + l15;
            mv[wid & 1][rl][0] = b1; mi[wid & 1][rl][0] = i1;
            mv[wid & 1][rl][1] = b2; mi[wid & 1][rl][1] = i2;
        }
    }
    __syncthreads();
    if (tid < 128) {
        float b1 = mv[0][tid][0], b2 = mv[0][tid][1];
        int   i1 = mi[0][tid][0], i2 = mi[0][tid][1];
#pragma unroll
        for (int sl = 0; sl < 2; ++sl) {
            float o = mv[1][tid][sl]; int oi = mi[1][tid][sl];
            if (better(o, oi, b1, i1)) { b2 = b1; i2 = i1; b1 = o; i1 = oi; }
            else if (better(o, oi, b2, i2)) { b2 = o; i2 = oi; }
        }
        size_t off = ((size_t)(r0 + tid) * NCB + vblk) * 2;
        pval[off] = b1;     pidx[off] = i1;
        pval[off + 1] = b2; pidx[off + 1] = i2;
    }
#undef STAGE_SC
}

// ---------------------------------------------------------------------------
// Kernel D: top-8 candidates per row from the 500 partials (approx ranking)
// ---------------------------------------------------------------------------
__global__ __launch_bounds__(256) void k_topk8(const float* __restrict__ pval,
                                               const int* __restrict__ pidx,
                                               int* __restrict__ cands) {
    int r = blockIdx.x, t = threadIdx.x;
    __shared__ float v[512];
    __shared__ int  id[512];
    for (int c = t; c < 512; c += 256) {
        if (c < NCB * 2) { v[c] = pval[(size_t)r * NCB * 2 + c]; id[c] = pidx[(size_t)r * NCB * 2 + c]; }
        else             { v[c] = NEG_INF; id[c] = 0x7fffffff; }
    }
    __syncthreads();
    if (t == 0) {
        float bv[NCAND]; int bi[NCAND];
#pragma unroll
        for (int j = 0; j < NCAND; ++j) { bv[j] = NEG_INF; bi[j] = 0x7fffffff; }
        for (int c = 0; c < NCB * 2; ++c) {
            float x = v[c]; int xi = id[c];
            if (better(x, xi, bv[NCAND - 1], bi[NCAND - 1])) {
                int j = NCAND - 1;
                while (j > 0 && better(x, xi, bv[j - 1], bi[j - 1])) {
                    bv[j] = bv[j - 1]; bi[j] = bi[j - 1]; --j;
                }
                bv[j] = x; bi[j] = xi;
            }
        }
#pragma unroll
        for (int j = 0; j < NCAND; ++j) cands[r * NCAND + j] = bi[j];
    }
}

// ---------------------------------------------------------------------------
// Kernel E: exact fp32 rescore of 8 candidates/row -> final top-2 + values
// ---------------------------------------------------------------------------
__global__ __launch_bounds__(256) void k_rescore(const float* __restrict__ s,
                                                 const float* __restrict__ T,
                                                 const int* __restrict__ cands,
                                                 const float* __restrict__ invw,
                                                 const float* __restrict__ invp,
                                                 float* __restrict__ outv,
                                                 int* __restrict__ tidx) {
    int r = blockIdx.x, t = threadIdx.x;
    int cg = t >> 5, l32 = t & 31;          // 8 groups of 32 lanes
    int c = cands[r * NCAND + cg];
    const float* Trow = T + (size_t)c * D_;
    const float* srow = s + (size_t)r * D_;
    float p = 0.f;
#pragma unroll
    for (int j = 0; j < 8; ++j) {
        int e = (j * 32 + l32) * 4;
        float4 a = *(const float4*)(srow + e);
        float4 b = *(const float4*)(Trow + e);
        p += a.x * b.x + a.y * b.y + a.z * b.z + a.w * b.w;
    }
#pragma unroll
    for (int off = 16; off >= 1; off >>= 1) p += __shfl_xor(p, off);  // stays in 32-group
    __shared__ float sc[NCAND];
    if (l32 == 0) sc[cg] = p;
    __syncthreads();
    if (t == 0) {
        float ip = invp[r];
        float b1 = NEG_INF, b2 = NEG_INF;
        int i1 = 0x7fffffff, i2 = 0x7fffffff;
#pragma unroll
        for (int j = 0; j < NCAND; ++j) {
            int ci = cands[r * NCAND + j];
            float val = sc[j] * invw[ci] * ip;
            if (better(val, ci, b1, i1)) { b2 = b1; i2 = i1; b1 = val; i1 = ci; }
            else if (better(val, ci, b2, i2)) { b2 = val; i2 = ci; }
        }
        outv[(size_t)r * 2 + 0] = b1;
        outv[(size_t)r * 2 + 1] = b2;
        tidx[r * 2 + 0] = i1;
        tidx[r * 2 + 1] = i2;
    }
}

// ---------------------------------------------------------------------------
// Kernel F: Z[r, 0:2, :] = T[idx], Z[r, 2:6, :] = P[r, :, :]
// ---------------------------------------------------------------------------
__global__ __launch_bounds__(256) void k_writeZ(const float* __restrict__ P,
                                                const float* __restrict__ T,
                                                const int* __restrict__ tidx,
                                                float* __restrict__ out) {
    int blk = blockIdx.x;  // r*6 + j
    int r = blk / 6, j = blk - r * 6;
    const float* src;
    if (j < KTOP) src = T + (size_t)tidx[r * 2 + j] * D_;
    else          src = P + ((size_t)r * NP_ + (j - KTOP)) * D_;
    float4 v = *(const float4*)(src + threadIdx.x * 4);
    *(float4*)(out + ((size_t)r * 6 + j) * D_ + threadIdx.x * 4) = v;
}

// ---------------------------------------------------------------------------
extern "C" void kernel_launch(void* const* d_in, const int* in_sizes, int n_in,
                              void* d_out, int out_size, void* d_ws, size_t ws_size,
                              hipStream_t stream) {
    const float* P   = (const float*)d_in[0];  // [32,64,4,1024]
    const float* we  = (const float*)d_in[1];  // [1024,768]
    const float* few = (const float*)d_in[2];  // [32000,768]
    const float* feb = (const float*)d_in[3];  // [32000]
    float* out = (float*)d_out;                // Z (12,582,912) then values (4096)
    float* ws  = (float*)d_ws;

    float* T    = ws + T_OFF;
    float* s    = ws + S_OFF;
    float* invw = ws + INVW_OFF;
    float* invp = ws + INVP_OFF;
    float* wsq  = ws + WSQ_OFF;
    float* pval = ws + PV_OFF;
    int*   pidx = (int*)(ws + PI_OFF);
    unsigned short* sb  = (unsigned short*)(ws + SB_OFF);
    unsigned short* Tb  = (unsigned short*)(ws + TB_OFF);
    unsigned short* weh = (unsigned short*)(ws + WH_OFF);
    unsigned short* wel = (unsigned short*)(ws + WL_OFF);
    int*   cands = (int*)(ws + CAND_OFF);
    int*   tidx  = (int*)(ws + TIDX_OFF);
    float* outv = out + (size_t)R_ * 6 * D_;

    k_zero<<<(VC_ + 255) / 256, 256, 0, stream>>>(wsq);
    k_split_we<<<(D_ * E_) / 1024, 256, 0, stream>>>(we, weh, wel);
    k_sum_pnorm<<<R_, 256, 0, stream>>>(P, s, sb, invp);
    k_gemm_T_mfma<<<2000, 256, 0, stream>>>(few, weh, wel, feb, T, Tb, wsq);
    k_invw<<<(VC_ + 255) / 256, 256, 0, stream>>>(wsq, invw);
    k_scores_mfma<<<4000, 256, 0, stream>>>(Tb, sb, invw, pval, pidx);
    k_topk8<<<R_, 256, 0, stream>>>(pval, pidx, cands);
    k_rescore<<<R_, 256, 0, stream>>>(s, T, cands, invw, invp, outv, tidx);
    k_writeZ<<<R_ * 6, 256, 0, stream>>>(P, T, tidx, out);
}